// Round 1
// baseline (621.779 us; speedup 1.0000x reference)
//
#include <hip/hip_runtime.h>
#include <hip/hip_bf16.h>

// Fused InvertedResidual, v2:
//   prep: fold BN1 into W2 (+bias1), BN2+BN3 into W3 (+bias3), transpose dw weights.
//   t0:   transpose+convert x2 -> xt[b][p][120] bf16 (LDS-tiled, coalesced both sides).
//   k1:   conv1x1 #1 (GEMM, A-frags = vector loads from xt) + prelu -> h1 in LDS
//         -> dwconv3x3 (regs) -> h2 into LDS (reuse h1 region)
//         -> conv1x1 #2 (GEMM from LDS) + bias3 + prelu -> odd out channels
//         -> strided copy of x1 -> even out channels.   (h2 global round-trip + k2 gone)

#define BATCH 64
#define CTOT  232
#define BFC   116
#define HW    3136
#define WD    56
#define CH2   120          // xt/h1/h2 channel stride (15 octets)
#define EPSV  1e-5f

typedef unsigned short u16;
typedef __attribute__((ext_vector_type(8))) short short8;
typedef __attribute__((ext_vector_type(4))) float float4v;

// d_ws layout (bytes)
#define WS_W2P   0          // u16[128*128]
#define WS_W3P   32768      // u16[128*128]
#define WS_WDWT  65536      // float[9*120]
#define WS_B1P   69888      // float[128]
#define WS_B3P   70400      // float[128]
#define WS_XT    131072     // u16[64*3136*120] = 48,168,960 B (total 48.3 MB < 51.38 MB known-safe)

__device__ __forceinline__ u16 f2bf(float f) {
    union { float f; unsigned u; } v; v.f = f;
    unsigned r = v.u + 0x7FFF + ((v.u >> 16) & 1);
    return (u16)(r >> 16);
}
__device__ __forceinline__ float bf2f(u16 u) {
    union { unsigned u; float f; } v; v.u = ((unsigned)u) << 16;
    return v.f;
}

// ---------------- prep: weight folding ----------------
__global__ __launch_bounds__(256) void prep(
    const float* __restrict__ w2, const float* __restrict__ g1, const float* __restrict__ b1,
    const float* __restrict__ m1, const float* __restrict__ v1,
    const float* __restrict__ wdw,
    const float* __restrict__ g2, const float* __restrict__ b2,
    const float* __restrict__ m2, const float* __restrict__ v2,
    const float* __restrict__ w3, const float* __restrict__ g3, const float* __restrict__ b3,
    const float* __restrict__ m3, const float* __restrict__ v3,
    char* __restrict__ ws) {
    u16* w2p = (u16*)(ws + WS_W2P);
    u16* w3p = (u16*)(ws + WS_W3P);
    float* wdwt = (float*)(ws + WS_WDWT);
    float* b1p = (float*)(ws + WS_B1P);
    float* b3p = (float*)(ws + WS_B3P);
    int tid = threadIdx.x;
    int bx = blockIdx.x;
    if (bx < 8) {                                  // w2p = sc1[o] * w2[o][c], padded 128x128
        int o = bx * 16 + (tid >> 4);
        int cs = (tid & 15) * 8;
        float sc = (o < BFC) ? g1[o] * rsqrtf(v1[o] + EPSV) : 0.f;
        short8 v;
        for (int j = 0; j < 8; j++) {
            int c = cs + j;
            float val = (o < BFC && c < BFC) ? sc * w2[o * BFC + c] : 0.f;
            ((u16*)&v)[j] = f2bf(val);
        }
        *(short8*)&w2p[o * 128 + cs] = v;
    } else if (bx < 16) {                          // w3p = sc3[o]*sc2[c]*w3[o][c]
        int o = (bx - 8) * 16 + (tid >> 4);
        int cs = (tid & 15) * 8;
        float sc = (o < BFC) ? g3[o] * rsqrtf(v3[o] + EPSV) : 0.f;
        short8 v;
        for (int j = 0; j < 8; j++) {
            int c = cs + j;
            float val = 0.f;
            if (o < BFC && c < BFC) {
                float sc2 = g2[c] * rsqrtf(v2[c] + EPSV);
                val = sc * sc2 * w3[o * BFC + c];
            }
            ((u16*)&v)[j] = f2bf(val);
        }
        *(short8*)&w3p[o * 128 + cs] = v;
    } else {
        if (tid < CH2)                             // dw weights transposed [tap][c]
            for (int tap = 0; tap < 9; tap++)
                wdwt[tap * CH2 + tid] = (tid < BFC) ? wdw[tid * 9 + tap] : 0.f;
        if (tid < 128) {
            float b1v = 0.f, b3v = 0.f;
            if (tid < BFC) {
                float sc1 = g1[tid] * rsqrtf(v1[tid] + EPSV);
                b1v = b1[tid] - m1[tid] * sc1;
                float sc3 = g3[tid] * rsqrtf(v3[tid] + EPSV);
                float s = 0.f;
                for (int c = 0; c < BFC; c++) {     // fold bn2 shift through w3
                    float sc2 = g2[c] * rsqrtf(v2[c] + EPSV);
                    float sh2 = b2[c] - m2[c] * sc2;
                    s += w3[tid * BFC + c] * sh2;
                }
                b3v = (b3[tid] - m3[tid] * sc3) + sc3 * s;
            }
            b1p[tid] = b1v;
            b3p[tid] = b3v;
        }
    }
}

// ---------------- t0: x2 [c][p] f32 -> xt [p][120] bf16 ----------------
__global__ __launch_bounds__(256) void t0(const float* __restrict__ x, char* __restrict__ ws) {
    __shared__ u16 lt[64 * CH2];                   // 15,360 B
    int tid = threadIdx.x;
    int b = blockIdx.y;
    int px0 = blockIdx.x * 64;
    const float* x2 = x + ((size_t)b * CTOT + BFC) * HW;
    u16* xt = (u16*)(ws + WS_XT);
    // zero pad ch 116..119 (one write per thread)
    lt[(tid >> 2) * CH2 + BFC + (tid & 3)] = 0;
    // stage: channel-pairs -> 4B LDS writes, coalesced float4 global reads
    for (int u = tid; u < 58 * 16; u += 256) {
        int c2 = u >> 4, i = u & 15;               // c = 2*c2, 4 px per item
        int c = c2 * 2;
        int p = px0 + i * 4;
        float4v va = *(const float4v*)&x2[(size_t)c * HW + p];
        float4v vb = *(const float4v*)&x2[(size_t)(c + 1) * HW + p];
        #pragma unroll
        for (int j = 0; j < 4; j++) {
            unsigned pair = (unsigned)f2bf(va[j]) | ((unsigned)f2bf(vb[j]) << 16);
            *(unsigned*)&lt[(i * 4 + j) * CH2 + c] = pair;
        }
    }
    __syncthreads();
    // write out: fully coalesced 16B stores
    for (int u = tid; u < 64 * 15; u += 256) {
        int px = u / 15, oct = u % 15;
        short8 v = *(const short8*)&lt[px * CH2 + oct * 8];
        *(short8*)&xt[((size_t)b * HW + px0 + px) * CH2 + oct * 8] = v;
    }
}

// ---------------- dwconv worker: one (px-quad, octet) item -> 4 bf16x8 rows ----
__device__ __forceinline__ void dw_compute(const u16* h1s, const float* __restrict__ wdwt,
                                           int u, short8 hrow[4]) {
    int oct = u % 15;
    int pq = u / 15;
    int rr = pq / 14;
    int col0 = (pq % 14) * 4;
    float acc[4][8];
    #pragma unroll
    for (int i = 0; i < 4; i++)
        #pragma unroll
        for (int j = 0; j < 8; j++) acc[i][j] = 0.f;
    #pragma unroll
    for (int dy = 0; dy < 3; dy++) {
        int lr = rr + dy;                          // h1s rows rr..rr+2
        float f[6][8];
        #pragma unroll
        for (int k = 0; k < 6; k++) {
            int ci = col0 - 1 + k;
            if (ci >= 0 && ci < WD) {
                short8 v = *(const short8*)&h1s[(lr * WD + ci) * CH2 + oct * 8];
                #pragma unroll
                for (int j = 0; j < 8; j++) f[k][j] = bf2f(((const u16*)&v)[j]);
            } else {
                #pragma unroll
                for (int j = 0; j < 8; j++) f[k][j] = 0.f;
            }
        }
        #pragma unroll
        for (int dx = 0; dx < 3; dx++) {
            const float* wt = &wdwt[(dy * 3 + dx) * CH2 + oct * 8];
            float4v w0 = *(const float4v*)&wt[0];
            float4v w1 = *(const float4v*)&wt[4];
            float w8[8] = {w0[0], w0[1], w0[2], w0[3], w1[0], w1[1], w1[2], w1[3]};
            #pragma unroll
            for (int i = 0; i < 4; i++)
                #pragma unroll
                for (int j = 0; j < 8; j++)
                    acc[i][j] += f[i + dx][j] * w8[j];
        }
    }
    #pragma unroll
    for (int i = 0; i < 4; i++) {
        short8 ov;
        #pragma unroll
        for (int j = 0; j < 8; j++) ((u16*)&ov)[j] = f2bf(acc[i][j]);
        hrow[i] = ov;
    }
}

// ---------------- k1: GEMM1 -> h1(LDS) -> dwconv -> h2(LDS) -> GEMM2 -> out ----
__global__ __launch_bounds__(256, 3) void k1(const float* __restrict__ x,
        const float* __restrict__ al1, const float* __restrict__ al2,
        char* __restrict__ ws, float* __restrict__ out) {
    __shared__ u16 h1s[224 * CH2];                 // 53,760 B -> 3 blocks/CU
    const u16* w2p = (const u16*)(ws + WS_W2P);
    const u16* w3p = (const u16*)(ws + WS_W3P);
    const float* wdwt = (const float*)(ws + WS_WDWT);
    const float* b1p = (const float*)(ws + WS_B1P);
    const float* b3p = (const float*)(ws + WS_B3P);
    const u16* xt = (const u16*)(ws + WS_XT);

    int tid = threadIdx.x;
    int lane = tid & 63;
    int w = tid >> 6;
    int l15 = lane & 15, kq = lane >> 4;
    int b = blockIdx.y;
    int r0 = blockIdx.x * 2;                       // 2 output rows per block
    int p_in0 = r0 * WD - WD;                      // strip rows r0-1 .. r0+2 (224 px)
    int p_out0 = r0 * WD;

    const u16* xtb = xt + (size_t)b * HW * CH2;
    float a1 = al1[0];
    short8 z8 = {0, 0, 0, 0, 0, 0, 0, 0};

    // ---- Phase A: GEMM1, waves split 2x2 (M-half x N-half), A from xt ----
    int mh = w >> 1, nh = w & 1;
    {
        short8 bfr[4][4];
        float biasv[4];
        for (int ni = 0; ni < 4; ni++) {
            int o = (nh * 4 + ni) * 16 + l15;
            #pragma unroll
            for (int kt = 0; kt < 4; kt++)
                bfr[ni][kt] = *(const short8*)&w2p[o * 128 + kt * 32 + kq * 8];
            biasv[ni] = b1p[o];
        }
        #pragma unroll
        for (int mi = 0; mi < 7; mi++) {
            int mt = mh * 7 + mi;
            int p = p_in0 + mt * 16 + l15;
            bool pv = (p >= 0) && (p < HW);
            const u16* arow = xtb + (size_t)p * CH2;
            short8 afr[4];
            #pragma unroll
            for (int kt = 0; kt < 4; kt++) {
                short8 av = z8;
                if (pv && !(kt == 3 && kq == 3)) av = *(const short8*)&arow[kt * 32 + kq * 8];
                afr[kt] = av;
            }
            for (int ni = 0; ni < 4; ni++) {
                float4v acc = {0.f, 0.f, 0.f, 0.f};
                #pragma unroll
                for (int kt = 0; kt < 4; kt++)
                    acc = __builtin_amdgcn_mfma_f32_16x16x32_bf16(afr[kt], bfr[ni][kt], acc, 0, 0, 0);
                int o = (nh * 4 + ni) * 16 + l15;
                if (o < CH2) {
                    int plb = mt * 16 + kq * 4;
                    #pragma unroll
                    for (int r = 0; r < 4; r++) {
                        int pl = plb + r;
                        int pim = p_in0 + pl;
                        float y = acc[r] + biasv[ni];
                        y = y >= 0.f ? y : a1 * y;
                        // out-of-image rows must be ZERO in h1 (dwconv zero-padding)
                        h1s[pl * CH2 + o] = (pim >= 0 && pim < HW) ? f2bf(y) : (u16)0;
                    }
                }
            }
        }
    }
    __syncthreads();

    // ---- Phase B: dwconv3x3 into registers (bn2 folded into w3p/bias3) ----
    short8 hA[4], hB[4];
    int uA = tid, uB = tid + 256;                  // 420 items over 256 threads
    bool hasB = uB < 420;
    dw_compute(h1s, wdwt, uA, hA);
    if (hasB) dw_compute(h1s, wdwt, uB, hB);
    __syncthreads();                               // all h1 reads complete

    // store h2 into the (dead) h1s region as [112 px][120 ch] bf16
    {
        int oct = uA % 15, pq = uA / 15;
        int pl = (pq / 14) * WD + (pq % 14) * 4;
        #pragma unroll
        for (int i = 0; i < 4; i++)
            *(short8*)&h1s[(pl + i) * CH2 + oct * 8] = hA[i];
    }
    if (hasB) {
        int oct = uB % 15, pq = uB / 15;
        int pl = (pq / 14) * WD + (pq % 14) * 4;
        #pragma unroll
        for (int i = 0; i < 4; i++)
            *(short8*)&h1s[(pl + i) * CH2 + oct * 8] = hB[i];
    }
    __syncthreads();

    // ---- Phase C: GEMM2 from LDS h2 + bias3 + prelu -> odd out channels ----
    {
        float a2 = al2[0];
        short8 cfr[4][4];
        float bias3v[4];
        for (int ni = 0; ni < 4; ni++) {
            int o = (nh * 4 + ni) * 16 + l15;
            #pragma unroll
            for (int kt = 0; kt < 4; kt++)
                cfr[ni][kt] = *(const short8*)&w3p[o * 128 + kt * 32 + kq * 8];
            bias3v[ni] = b3p[o];
        }
        #pragma unroll
        for (int mi = 0; mi < 4; mi++) {
            int mt = mh * 4 + mi;                  // 7 m-tiles: waves get 4 / 3
            if (mt < 7) {
                int pl = mt * 16 + l15;
                const u16* arow = &h1s[pl * CH2];
                short8 afr[4];
                #pragma unroll
                for (int kt = 0; kt < 4; kt++) {
                    short8 av = z8;
                    if (!(kt == 3 && kq == 3)) av = *(const short8*)&arow[kt * 32 + kq * 8];
                    afr[kt] = av;
                }
                for (int ni = 0; ni < 4; ni++) {
                    float4v acc = {0.f, 0.f, 0.f, 0.f};
                    #pragma unroll
                    for (int kt = 0; kt < 4; kt++)
                        acc = __builtin_amdgcn_mfma_f32_16x16x32_bf16(afr[kt], cfr[ni][kt], acc, 0, 0, 0);
                    int o = (nh * 4 + ni) * 16 + l15;
                    int pq = mt * 16 + kq * 4;
                    if (o < BFC) {
                        float4v ov;
                        #pragma unroll
                        for (int r = 0; r < 4; r++) {
                            float y = acc[r] + bias3v[ni];
                            ov[r] = y >= 0.f ? y : a2 * y;
                        }
                        *(float4v*)&out[((size_t)b * CTOT + 2 * o + 1) * HW + p_out0 + pq] = ov;
                    }
                }
            }
        }
    }

    // ---- Phase D: copy x1 strip -> even out channels (folded shuffle) ----
    {
        const float* x1 = x + (size_t)b * CTOT * HW;
        for (int u = tid; u < BFC * 28; u += 256) {
            int c = u / 28, i = u % 28;            // 28 float4 = 112 px
            float4v v = *(const float4v*)&x1[(size_t)c * HW + p_out0 + i * 4];
            *(float4v*)&out[((size_t)b * CTOT + 2 * c) * HW + p_out0 + i * 4] = v;
        }
    }
}

extern "C" void kernel_launch(void* const* d_in, const int* in_sizes, int n_in,
                              void* d_out, int out_size, void* d_ws, size_t ws_size,
                              hipStream_t stream) {
    const float* x   = (const float*)d_in[0];
    const float* w2  = (const float*)d_in[1];
    const float* g1  = (const float*)d_in[2];
    const float* b1  = (const float*)d_in[3];
    const float* m1  = (const float*)d_in[4];
    const float* v1  = (const float*)d_in[5];
    const float* al1 = (const float*)d_in[6];
    const float* wdw = (const float*)d_in[7];
    const float* g2  = (const float*)d_in[8];
    const float* b2  = (const float*)d_in[9];
    const float* m2  = (const float*)d_in[10];
    const float* v2  = (const float*)d_in[11];
    const float* w3  = (const float*)d_in[12];
    const float* g3  = (const float*)d_in[13];
    const float* b3  = (const float*)d_in[14];
    const float* m3  = (const float*)d_in[15];
    const float* v3  = (const float*)d_in[16];
    const float* al2 = (const float*)d_in[17];
    float* out = (float*)d_out;
    char* ws = (char*)d_ws;

    hipLaunchKernelGGL(prep, dim3(17), dim3(256), 0, stream,
                       w2, g1, b1, m1, v1, wdw, g2, b2, m2, v2, w3, g3, b3, m3, v3, ws);
    hipLaunchKernelGGL(t0, dim3(HW / 64, BATCH), dim3(256), 0, stream, x, ws);
    hipLaunchKernelGGL(k1, dim3(28, BATCH), dim3(256), 0, stream, x, al1, al2, ws, out);
}

// Round 2
// 575.678 us; speedup vs baseline: 1.0801x; 1.0801x over previous
//
#include <hip/hip_runtime.h>
#include <hip/hip_bf16.h>

// Fused InvertedResidual, v3 — single compute kernel, no intermediate HBM round-trips:
//   prep: fold BN1 into W2 (+bias1), BN2+BN3 into W3 (+bias3), transpose dw weights.
//   k1 (per 2-row strip, XCD-chunk-swizzled grid):
//     Phase 0: stage x2 strip f32 -> bf16 LDS xs[224][120] (coalesced 128B reads).
//     Phase A: conv1x1 #1 GEMM in-place in LDS (h1 rows overwrite consumed A rows,
//              1 barrier per 16-row m-tile) + prelu; OOB rows zeroed.
//     Phase B: dwconv3x3 in regs -> h2 overwrites xs rows 0..111.
//     Phase C: conv1x1 #2 GEMM from LDS + bias3 + prelu -> odd out channels.
//     Phase D: copy x1 strip -> even out channels.

#define BATCH 64
#define CTOT  232
#define BFC   116
#define HW    3136
#define WD    56
#define CH2   120          // xs channel stride (15 octets)
#define EPSV  1e-5f

typedef unsigned short u16;
typedef __attribute__((ext_vector_type(8))) short short8;
typedef __attribute__((ext_vector_type(4))) float float4v;

// d_ws layout (bytes) — weights only now
#define WS_W2P   0          // u16[128*128]
#define WS_W3P   32768      // u16[128*128]
#define WS_WDWT  65536      // float[9*120]
#define WS_B1P   69888      // float[128]
#define WS_B3P   70400      // float[128]

__device__ __forceinline__ u16 f2bf(float f) {
    union { float f; unsigned u; } v; v.f = f;
    unsigned r = v.u + 0x7FFF + ((v.u >> 16) & 1);
    return (u16)(r >> 16);
}
__device__ __forceinline__ float bf2f(u16 u) {
    union { unsigned u; float f; } v; v.u = ((unsigned)u) << 16;
    return v.f;
}

// ---------------- prep: weight folding ----------------
__global__ __launch_bounds__(256) void prep(
    const float* __restrict__ w2, const float* __restrict__ g1, const float* __restrict__ b1,
    const float* __restrict__ m1, const float* __restrict__ v1,
    const float* __restrict__ wdw,
    const float* __restrict__ g2, const float* __restrict__ b2,
    const float* __restrict__ m2, const float* __restrict__ v2,
    const float* __restrict__ w3, const float* __restrict__ g3, const float* __restrict__ b3,
    const float* __restrict__ m3, const float* __restrict__ v3,
    char* __restrict__ ws) {
    u16* w2p = (u16*)(ws + WS_W2P);
    u16* w3p = (u16*)(ws + WS_W3P);
    float* wdwt = (float*)(ws + WS_WDWT);
    float* b1p = (float*)(ws + WS_B1P);
    float* b3p = (float*)(ws + WS_B3P);
    int tid = threadIdx.x;
    int bx = blockIdx.x;
    if (bx < 8) {                                  // w2p = sc1[o] * w2[o][c], padded 128x128
        int o = bx * 16 + (tid >> 4);
        int cs = (tid & 15) * 8;
        float sc = (o < BFC) ? g1[o] * rsqrtf(v1[o] + EPSV) : 0.f;
        short8 v;
        for (int j = 0; j < 8; j++) {
            int c = cs + j;
            float val = (o < BFC && c < BFC) ? sc * w2[o * BFC + c] : 0.f;
            ((u16*)&v)[j] = f2bf(val);
        }
        *(short8*)&w2p[o * 128 + cs] = v;
    } else if (bx < 16) {                          // w3p = sc3[o]*sc2[c]*w3[o][c]
        int o = (bx - 8) * 16 + (tid >> 4);
        int cs = (tid & 15) * 8;
        float sc = (o < BFC) ? g3[o] * rsqrtf(v3[o] + EPSV) : 0.f;
        short8 v;
        for (int j = 0; j < 8; j++) {
            int c = cs + j;
            float val = 0.f;
            if (o < BFC && c < BFC) {
                float sc2 = g2[c] * rsqrtf(v2[c] + EPSV);
                val = sc * sc2 * w3[o * BFC + c];
            }
            ((u16*)&v)[j] = f2bf(val);
        }
        *(short8*)&w3p[o * 128 + cs] = v;
    } else {
        if (tid < CH2)                             // dw weights transposed [tap][c]
            for (int tap = 0; tap < 9; tap++)
                wdwt[tap * CH2 + tid] = (tid < BFC) ? wdw[tid * 9 + tap] : 0.f;
        if (tid < 128) {
            float b1v = 0.f, b3v = 0.f;
            if (tid < BFC) {
                float sc1 = g1[tid] * rsqrtf(v1[tid] + EPSV);
                b1v = b1[tid] - m1[tid] * sc1;
                float sc3 = g3[tid] * rsqrtf(v3[tid] + EPSV);
                float s = 0.f;
                for (int c = 0; c < BFC; c++) {     // fold bn2 shift through w3
                    float sc2 = g2[c] * rsqrtf(v2[c] + EPSV);
                    float sh2 = b2[c] - m2[c] * sc2;
                    s += w3[tid * BFC + c] * sh2;
                }
                b3v = (b3[tid] - m3[tid] * sc3) + sc3 * s;
            }
            b1p[tid] = b1v;
            b3p[tid] = b3v;
        }
    }
}

// ---------------- dwconv worker: one (px-quad, octet) item -> 4 bf16x8 cols ----
__device__ __forceinline__ void dw_compute(const u16* xs, const float* __restrict__ wdwt,
                                           int u, short8 hrow[4]) {
    int oct = u % 15;
    int pq = u / 15;
    int rr = pq / 14;
    int col0 = (pq % 14) * 4;
    float acc[4][8];
    #pragma unroll
    for (int i = 0; i < 4; i++)
        #pragma unroll
        for (int j = 0; j < 8; j++) acc[i][j] = 0.f;
    #pragma unroll
    for (int dy = 0; dy < 3; dy++) {
        int lr = rr + dy;                          // xs rows rr..rr+2 (image rows)
        float f[6][8];
        #pragma unroll
        for (int k = 0; k < 6; k++) {
            int ci = col0 - 1 + k;
            if (ci >= 0 && ci < WD) {
                short8 v = *(const short8*)&xs[(lr * WD + ci) * CH2 + oct * 8];
                #pragma unroll
                for (int j = 0; j < 8; j++) f[k][j] = bf2f(((const u16*)&v)[j]);
            } else {
                #pragma unroll
                for (int j = 0; j < 8; j++) f[k][j] = 0.f;
            }
        }
        #pragma unroll
        for (int dx = 0; dx < 3; dx++) {
            const float* wt = &wdwt[(dy * 3 + dx) * CH2 + oct * 8];
            float4v w0 = *(const float4v*)&wt[0];
            float4v w1 = *(const float4v*)&wt[4];
            float w8[8] = {w0[0], w0[1], w0[2], w0[3], w1[0], w1[1], w1[2], w1[3]};
            #pragma unroll
            for (int i = 0; i < 4; i++)
                #pragma unroll
                for (int j = 0; j < 8; j++)
                    acc[i][j] += f[i + dx][j] * w8[j];
        }
    }
    #pragma unroll
    for (int i = 0; i < 4; i++) {
        short8 ov;
        #pragma unroll
        for (int j = 0; j < 8; j++) ((u16*)&ov)[j] = f2bf(acc[i][j]);
        hrow[i] = ov;
    }
}

// ---------------- k1: stage -> GEMM1(in-place) -> dwconv -> GEMM2 -> out ------
__global__ __launch_bounds__(256, 3) void k1(const float* __restrict__ x,
        const float* __restrict__ al1, const float* __restrict__ al2,
        const char* __restrict__ ws, float* __restrict__ out) {
    __shared__ u16 xs[224 * CH2];                  // 53,760 B -> 3 blocks/CU
    const u16* w2p = (const u16*)(ws + WS_W2P);
    const u16* w3p = (const u16*)(ws + WS_W3P);
    const float* wdwt = (const float*)(ws + WS_WDWT);
    const float* b1p = (const float*)(ws + WS_B1P);
    const float* b3p = (const float*)(ws + WS_B3P);

    int tid = threadIdx.x;
    int lane = tid & 63;
    int w = tid >> 6;
    int l15 = lane & 15, kq = lane >> 4;

    // XCD-chunk swizzle: 1792 = 8 XCDs x 224 strips; each XCD owns 8 whole
    // batches -> halo/boundary-line neighbor strips always share an L2.
    int L = blockIdx.x;
    int sw = (L & 7) * 224 + (L >> 3);
    int b = sw / 28;
    int s = sw - b * 28;
    int r0 = s * 2;                                // 2 output rows per block
    int p_in0 = r0 * WD - WD;                      // strip rows r0-1 .. r0+2 (224 px)
    int p_out0 = r0 * WD;

    const float* x2 = x + ((size_t)b * CTOT + BFC) * HW;
    float a1 = al1[0];
    float a2 = al2[0];
    short8 z8 = {0, 0, 0, 0, 0, 0, 0, 0};

    // ---- Phase 0: stage x2 strip f32 -> bf16 xs[224][120] ----
    // item u: qo = u&7 (px-quad within 8-group), c2 = (u>>3)&63 (channel pair),
    // q8 = u>>9. Lanes: 8 quads x 8 ch-pairs -> global 128B segments/channel.
    #pragma unroll 4
    for (int it = 0; it < 14; it++) {
        int u = it * 256 + tid;
        int c2 = (u >> 3) & 63;
        if (c2 < 60) {                             // ch 0..119 (58,59 = zero pad)
            int q = (u >> 9) * 8 + (u & 7);        // px-quad 0..55
            int p = p_in0 + q * 4;
            unsigned pr[4] = {0u, 0u, 0u, 0u};
            if (c2 < 58 && p >= 0 && p < HW) {
                int c = 2 * c2;
                float4v va = *(const float4v*)&x2[(size_t)c * HW + p];
                float4v vb = *(const float4v*)&x2[(size_t)(c + 1) * HW + p];
                #pragma unroll
                for (int j = 0; j < 4; j++)
                    pr[j] = (unsigned)f2bf(va[j]) | ((unsigned)f2bf(vb[j]) << 16);
            }
            int px = q * 4;
            #pragma unroll
            for (int j = 0; j < 4; j++)
                *(unsigned*)&xs[(px + j) * CH2 + 2 * c2] = pr[j];
        }
    }
    __syncthreads();

    // ---- Phase A: GEMM1 in-place (all waves on same m-tile; h1 overwrites A) --
    {
        short8 bfr[2][4];
        float biasv[2];
        for (int ni = 0; ni < 2; ni++) {
            int o = (2 * w + ni) * 16 + l15;
            #pragma unroll
            for (int kt = 0; kt < 4; kt++)
                bfr[ni][kt] = *(const short8*)&w2p[o * 128 + kt * 32 + kq * 8];
            biasv[ni] = b1p[o];
        }
        for (int mt = 0; mt < 14; mt++) {
            int pl = mt * 16 + l15;
            const u16* arow = &xs[pl * CH2];
            short8 afr[4];
            #pragma unroll
            for (int kt = 0; kt < 4; kt++) {
                short8 av = z8;
                if (!(kt == 3 && kq == 3)) av = *(const short8*)&arow[kt * 32 + kq * 8];
                afr[kt] = av;
            }
            float4v acc[2];
            #pragma unroll
            for (int ni = 0; ni < 2; ni++) {
                acc[ni] = (float4v){0.f, 0.f, 0.f, 0.f};
                #pragma unroll
                for (int kt = 0; kt < 4; kt++)
                    acc[ni] = __builtin_amdgcn_mfma_f32_16x16x32_bf16(afr[kt], bfr[ni][kt], acc[ni], 0, 0, 0);
            }
            __syncthreads();                       // all waves' reads of rows mt done
            #pragma unroll
            for (int ni = 0; ni < 2; ni++) {
                int o = (2 * w + ni) * 16 + l15;
                if (o < CH2) {
                    int plb = mt * 16 + kq * 4;
                    #pragma unroll
                    for (int r = 0; r < 4; r++) {
                        int pl2 = plb + r;
                        int pim = p_in0 + pl2;
                        float y = acc[ni][r] + biasv[ni];
                        y = y >= 0.f ? y : a1 * y;
                        // out-of-image rows must be ZERO (dwconv zero-padding)
                        xs[pl2 * CH2 + o] = (pim >= 0 && pim < HW) ? f2bf(y) : (u16)0;
                    }
                }
            }
        }
    }
    __syncthreads();

    // ---- Phase B: dwconv3x3 into registers, then h2 overwrites xs rows 0..111 --
    short8 hA[4], hB[4];
    int uA = tid, uB = tid + 256;                  // 420 items over 256 threads
    bool hasB = uB < 420;
    dw_compute(xs, wdwt, uA, hA);
    if (hasB) dw_compute(xs, wdwt, uB, hB);
    __syncthreads();                               // all h1 reads complete
    {
        int oct = uA % 15, pq = uA / 15;
        int pl = (pq / 14) * WD + (pq % 14) * 4;
        #pragma unroll
        for (int i = 0; i < 4; i++)
            *(short8*)&xs[(pl + i) * CH2 + oct * 8] = hA[i];
    }
    if (hasB) {
        int oct = uB % 15, pq = uB / 15;
        int pl = (pq / 14) * WD + (pq % 14) * 4;
        #pragma unroll
        for (int i = 0; i < 4; i++)
            *(short8*)&xs[(pl + i) * CH2 + oct * 8] = hB[i];
    }
    __syncthreads();

    // ---- Phase C: GEMM2 from LDS h2 + bias3 + prelu -> odd out channels ----
    {
        int mh = w >> 1, nh = w & 1;
        short8 cfr[4][4];
        float bias3v[4];
        for (int ni = 0; ni < 4; ni++) {
            int o = (nh * 4 + ni) * 16 + l15;
            #pragma unroll
            for (int kt = 0; kt < 4; kt++)
                cfr[ni][kt] = *(const short8*)&w3p[o * 128 + kt * 32 + kq * 8];
            bias3v[ni] = b3p[o];
        }
        #pragma unroll
        for (int mi = 0; mi < 4; mi++) {
            int mt = mh * 4 + mi;                  // 7 m-tiles: waves get 4 / 3
            if (mt < 7) {
                int pl = mt * 16 + l15;
                const u16* arow = &xs[pl * CH2];
                short8 afr[4];
                #pragma unroll
                for (int kt = 0; kt < 4; kt++) {
                    short8 av = z8;
                    if (!(kt == 3 && kq == 3)) av = *(const short8*)&arow[kt * 32 + kq * 8];
                    afr[kt] = av;
                }
                for (int ni = 0; ni < 4; ni++) {
                    float4v acc = {0.f, 0.f, 0.f, 0.f};
                    #pragma unroll
                    for (int kt = 0; kt < 4; kt++)
                        acc = __builtin_amdgcn_mfma_f32_16x16x32_bf16(afr[kt], cfr[ni][kt], acc, 0, 0, 0);
                    int o = (nh * 4 + ni) * 16 + l15;
                    int pq = mt * 16 + kq * 4;
                    if (o < BFC) {
                        float4v ov;
                        #pragma unroll
                        for (int r = 0; r < 4; r++) {
                            float y = acc[r] + bias3v[ni];
                            ov[r] = y >= 0.f ? y : a2 * y;
                        }
                        *(float4v*)&out[((size_t)b * CTOT + 2 * o + 1) * HW + p_out0 + pq] = ov;
                    }
                }
            }
        }
    }

    // ---- Phase D: copy x1 strip -> even out channels (folded shuffle) ----
    {
        const float* x1 = x + (size_t)b * CTOT * HW;
        for (int u = tid; u < BFC * 28; u += 256) {
            int c = u / 28, i = u % 28;            // 28 float4 = 112 px
            float4v v = *(const float4v*)&x1[(size_t)c * HW + p_out0 + i * 4];
            *(float4v*)&out[((size_t)b * CTOT + 2 * c) * HW + p_out0 + i * 4] = v;
        }
    }
}

extern "C" void kernel_launch(void* const* d_in, const int* in_sizes, int n_in,
                              void* d_out, int out_size, void* d_ws, size_t ws_size,
                              hipStream_t stream) {
    const float* x   = (const float*)d_in[0];
    const float* w2  = (const float*)d_in[1];
    const float* g1  = (const float*)d_in[2];
    const float* b1  = (const float*)d_in[3];
    const float* m1  = (const float*)d_in[4];
    const float* v1  = (const float*)d_in[5];
    const float* al1 = (const float*)d_in[6];
    const float* wdw = (const float*)d_in[7];
    const float* g2  = (const float*)d_in[8];
    const float* b2  = (const float*)d_in[9];
    const float* m2  = (const float*)d_in[10];
    const float* v2  = (const float*)d_in[11];
    const float* w3  = (const float*)d_in[12];
    const float* g3  = (const float*)d_in[13];
    const float* b3  = (const float*)d_in[14];
    const float* m3  = (const float*)d_in[15];
    const float* v3  = (const float*)d_in[16];
    const float* al2 = (const float*)d_in[17];
    float* out = (float*)d_out;
    char* ws = (char*)d_ws;

    hipLaunchKernelGGL(prep, dim3(17), dim3(256), 0, stream,
                       w2, g1, b1, m1, v1, wdw, g2, b2, m2, v2, w3, g3, b3, m3, v3, ws);
    hipLaunchKernelGGL(k1, dim3(28 * BATCH), dim3(256), 0, stream, x, al1, al2, ws, out);
}